// Round 11
// baseline (1026.054 us; speedup 1.0000x reference)
//
#include <hip/hip_runtime.h>
#include <hip/hip_fp16.h>

#define D 128
#define MAX_B 8192
#define MARGIN 1.0f

// ---------------- fused single kernel: block == type ----------------
// 512 thr = 8 waves. Block scans pos_type_r for its type (round-10 scheme),
// then each wave processes its samples autonomously. T is held in VGPRs as
// fp16 column-pairs: lane l owns cols {2l, 2l+1} x all 128 rows -> the matvec
// is fully in-lane (no T LDS reads, no cross-lane combine). v is broadcast
// from per-wave LDS via uniform-address b128 reads.

#define BFLY6(x) { x += __shfl_xor(x, 1); x += __shfl_xor(x, 2); x += __shfl_xor(x, 4); \
                   x += __shfl_xor(x, 8); x += __shfl_xor(x, 16); x += __shfl_xor(x, 32); }

struct SampleRegs {
    float2 e0, e1, e2, e3;   // ent rows {ph,pt,nh,nt}, elems {2l, 2l+1}
    float2 rp, rn;           // rel rows (pos, neg), cols {2l, 2l+1}
};

__device__ __forceinline__ void fetch_sample(
    SampleRegs& S, int o,
    const float* __restrict__ ent, const float* __restrict__ rel,
    const int* __restrict__ pos_h, const int* __restrict__ pos_t,
    const int* __restrict__ pos_r, const int* __restrict__ neg_h,
    const int* __restrict__ neg_t, const int* __restrict__ neg_r,
    int l)
{
    const size_t b0 = (size_t)pos_h[o] * D;
    const size_t b1 = (size_t)pos_t[o] * D;
    const size_t b2 = (size_t)neg_h[o] * D;
    const size_t b3 = (size_t)neg_t[o] * D;
    const size_t r0 = (size_t)pos_r[o] * D;
    const size_t r1 = (size_t)neg_r[o] * D;
    S.e0 = *(const float2*)&ent[b0 + 2 * l];
    S.e1 = *(const float2*)&ent[b1 + 2 * l];
    S.e2 = *(const float2*)&ent[b2 + 2 * l];
    S.e3 = *(const float2*)&ent[b3 + 2 * l];
    S.rp = *(const float2*)&rel[r0 + 2 * l];
    S.rn = *(const float2*)&rel[r1 + 2 * l];
}

__device__ __forceinline__ void commit_sample(float* vbw, const SampleRegs& S, int l) {
    *(float2*)&vbw[0 * D + 2 * l] = S.e0;
    *(float2*)&vbw[1 * D + 2 * l] = S.e1;
    *(float2*)&vbw[2 * D + 2 * l] = S.e2;
    *(float2*)&vbw[3 * D + 2 * l] = S.e3;
}

// one d-row: tf = fp32(T[d][2l..2l+1]); acc_role += tf * v_role[d]
#define STEP(TH, V0, V1, V2, V3) do {                                  \
        const float2 tf = __half22float2(TH);                          \
        a0.x = fmaf(tf.x, (V0), a0.x); a0.y = fmaf(tf.y, (V0), a0.y);  \
        a1.x = fmaf(tf.x, (V1), a1.x); a1.y = fmaf(tf.y, (V1), a1.y);  \
        a2.x = fmaf(tf.x, (V2), a2.x); a2.y = fmaf(tf.y, (V2), a2.y);  \
        a3.x = fmaf(tf.x, (V3), a3.x); a3.y = fmaf(tf.y, (V3), a3.y);  \
    } while (0)

__device__ __forceinline__ float sample_score(
    const __half2 (&Treg)[128], const float* __restrict__ vbw,
    float2 rp, float2 rn)
{
    const float4* __restrict__ v0p = (const float4*)(vbw);
    const float4* __restrict__ v1p = (const float4*)(vbw + D);
    const float4* __restrict__ v2p = (const float4*)(vbw + 2 * D);
    const float4* __restrict__ v3p = (const float4*)(vbw + 3 * D);
    float2 a0 = make_float2(0.f, 0.f), a1 = a0, a2 = a0, a3 = a0;
    #pragma unroll
    for (int dg = 0; dg < 32; ++dg) {
        const float4 w0 = v0p[dg];     // uniform-address broadcast b128
        const float4 w1 = v1p[dg];
        const float4 w2 = v2p[dg];
        const float4 w3 = v3p[dg];
        STEP(Treg[4 * dg + 0], w0.x, w1.x, w2.x, w3.x);
        STEP(Treg[4 * dg + 1], w0.y, w1.y, w2.y, w3.y);
        STEP(Treg[4 * dg + 2], w0.z, w1.z, w2.z, w3.z);
        STEP(Treg[4 * dg + 3], w0.w, w1.w, w2.w, w3.w);
    }
    float sph = a0.x * a0.x + a0.y * a0.y;
    float spt = a1.x * a1.x + a1.y * a1.y;
    float snh = a2.x * a2.x + a2.y * a2.y;
    float snt = a3.x * a3.x + a3.y * a3.y;
    float spr = rp.x * rp.x + rp.y * rp.y;
    float snr = rn.x * rn.x + rn.y * rn.y;
    BFLY6(sph); BFLY6(spt); BFLY6(snh); BFLY6(snt); BFLY6(spr); BFLY6(snr);
    const float iph = rsqrtf(sph + 1e-12f);
    const float ipt = rsqrtf(spt + 1e-12f);
    const float inh = rsqrtf(snh + 1e-12f);
    const float itn = rsqrtf(snt + 1e-12f);
    const float ipr = rsqrtf(spr + 1e-12f);
    const float inr = rsqrtf(snr + 1e-12f);
    float z = fabsf(a0.x * iph + rp.x * ipr - a1.x * ipt)
            + fabsf(a0.y * iph + rp.y * ipr - a1.y * ipt)
            - fabsf(a2.x * inh + rn.x * inr - a3.x * itn)
            - fabsf(a2.y * inh + rn.y * inr - a3.y * itn);
    BFLY6(z);
    return fmaxf(z + MARGIN, 0.f);
}

__global__ __launch_bounds__(512) void fused_kernel(
    const float* __restrict__ ent,
    const float* __restrict__ rel,
    const float* __restrict__ tmat,
    const int* __restrict__ pos_h,
    const int* __restrict__ pos_t,
    const int* __restrict__ pos_r,
    const int* __restrict__ type_r,
    const int* __restrict__ neg_h,
    const int* __restrict__ neg_t,
    const int* __restrict__ neg_r,
    float* __restrict__ out,
    int B, float inv_B)
{
    const int t   = blockIdx.x;        // this block's type
    const int tid = threadIdx.x;
    const int l   = tid & 63;
    const int w   = tid >> 6;          // wave 0..7

    __shared__ float vbuf[8][4][D];    // 16 KB per-wave role-major v buffers
    __shared__ int   list[64];
    __shared__ int   wsumi[8];
    __shared__ float wsumf[8];

    // ---- scan pos_type_r: thread tid covers samples [tid*per, +per) ----
    const int per = (B + 511) >> 9;    // == 16 at B=8192
    int vals[16];
    const int base = tid * per;
    int mc = 0;
    if (per == 16 && base + 15 < B) {
        const int4* vp = (const int4*)(type_r + base);
        #pragma unroll
        for (int k = 0; k < 4; ++k) {
            const int4 v = vp[k];
            vals[4*k+0] = v.x; vals[4*k+1] = v.y;
            vals[4*k+2] = v.z; vals[4*k+3] = v.w;
        }
    } else {
        for (int j = 0; j < 16; ++j) {
            const int s = base + j;
            vals[j] = (j < per && s < B) ? type_r[s] : -1;
        }
    }
    #pragma unroll
    for (int j = 0; j < 16; ++j) mc += (vals[j] == t);

    // ---- T into VGPRs as fp16 column pairs (coalesced b64 global loads) ----
    __half2 Treg[128];
    {
        const float* Tg = tmat + (size_t)t * (D * D) + 2 * l;
        #pragma unroll
        for (int d = 0; d < 128; ++d) {
            const float2 tc = *(const float2*)(Tg + d * D);
            Treg[d] = __float22half2_rn(tc);
        }
    }

    // ---- block-wide exclusive prefix of mc ----
    int inc = mc;
    #pragma unroll
    for (int off = 1; off < 64; off <<= 1) {
        const int tv = __shfl_up(inc, off);
        if (l >= off) inc += tv;
    }
    if (l == 63) wsumi[w] = inc;
    __syncthreads();
    int wbase = 0, cnt = 0;
    #pragma unroll
    for (int k = 0; k < 8; ++k) {
        const int s = wsumi[k];
        wbase += (k < w) ? s : 0;
        cnt += s;
    }
    const int excl = wbase + inc - mc;

    float wl = 0.f;
    for (int r0 = 0;; r0 += 64) {
        // write this round's window [r0, r0+64) of the ordered match list
        {
            int g = excl;
            #pragma unroll
            for (int j = 0; j < 16; ++j) {
                if (vals[j] == t) {
                    const int wr = g - r0;
                    if (wr >= 0 && wr < 64) list[wr] = base + j;
                    ++g;
                }
            }
        }
        __syncthreads();               // list visible
        const int wcnt = min(cnt - r0, 64);
        int sidx[8];
        int nk = 0;
        #pragma unroll
        for (int k = 0; k < 8; ++k) {
            const int rank = w + 8 * k;
            if (rank < wcnt) sidx[nk++] = list[rank];
        }
        __syncthreads();               // reads done before next window write

        if (nk > 0) {
            float* vbw = &vbuf[w][0][0];
            SampleRegs A, Bq;
            fetch_sample(A, sidx[0], ent, rel, pos_h, pos_t, pos_r,
                         neg_h, neg_t, neg_r, l);
            for (int k = 0;; ++k) {
                commit_sample(vbw, A, l);
                const bool more = (k + 1) < nk;
                if (more)
                    fetch_sample(Bq, sidx[k + 1], ent, rel, pos_h, pos_t, pos_r,
                                 neg_h, neg_t, neg_r, l);
                wl += sample_score(Treg, vbw, A.rp, A.rn);
                if (!more) break;
                A = Bq;
            }
        }
        if (r0 + 64 >= cnt) break;
    }

    // ---- block reduction, one atomic ----
    __syncthreads();
    if (l == 0) wsumf[w] = wl;
    __syncthreads();
    if (tid == 0) {
        float s = 0.f;
        #pragma unroll
        for (int k = 0; k < 8; ++k) s += wsumf[k];
        if (s != 0.f) atomicAdd(out, s * inv_B);
    }
}

// ---------------- fallback (round-1 per-sample kernel) ----------------

__global__ __launch_bounds__(128) void transr_fallback(
    const float* __restrict__ ent, const float* __restrict__ rel,
    const float* __restrict__ tmat,
    const int* __restrict__ pos_h, const int* __restrict__ pos_t,
    const int* __restrict__ pos_r, const int* __restrict__ pos_type_r,
    const int* __restrict__ neg_h, const int* __restrict__ neg_t,
    const int* __restrict__ neg_r, float* __restrict__ out, int B)
{
    const int b = blockIdx.x;
    const int r = threadIdx.x;
    const int lane = r & 63;
    const int wid = r >> 6;
    __shared__ float4 vcomb[D];
    __shared__ float sred[16];
    vcomb[r] = make_float4(ent[(size_t)pos_h[b]*D + r], ent[(size_t)pos_t[b]*D + r],
                           ent[(size_t)neg_h[b]*D + r], ent[(size_t)neg_t[b]*D + r]);
    const float prr = rel[(size_t)pos_r[b] * D + r];
    const float nrr = rel[(size_t)neg_r[b] * D + r];
    __syncthreads();
    const float* __restrict__ T = tmat + (size_t)pos_type_r[b] * (D * D);
    float aph = 0.f, apt = 0.f, anh = 0.f, ant = 0.f;
    #pragma unroll 8
    for (int d = 0; d < D; ++d) {
        const float t = T[d * D + r];
        const float4 v = vcomb[d];
        aph = fmaf(v.x, t, aph); apt = fmaf(v.y, t, apt);
        anh = fmaf(v.z, t, anh); ant = fmaf(v.w, t, ant);
    }
    float s0 = aph*aph, s1 = apt*apt, s2 = anh*anh, s3 = ant*ant;
    float s4 = prr*prr, s5 = nrr*nrr;
    #pragma unroll
    for (int off = 32; off; off >>= 1) {
        s0 += __shfl_xor(s0, off); s1 += __shfl_xor(s1, off);
        s2 += __shfl_xor(s2, off); s3 += __shfl_xor(s3, off);
        s4 += __shfl_xor(s4, off); s5 += __shfl_xor(s5, off);
    }
    if (lane == 0) {
        sred[wid*8+0]=s0; sred[wid*8+1]=s1; sred[wid*8+2]=s2;
        sred[wid*8+3]=s3; sred[wid*8+4]=s4; sred[wid*8+5]=s5;
    }
    __syncthreads();
    const float iph = rsqrtf(sred[0]+sred[8] +1e-12f);
    const float ipt = rsqrtf(sred[1]+sred[9] +1e-12f);
    const float inh = rsqrtf(sred[2]+sred[10]+1e-12f);
    const float itn = rsqrtf(sred[3]+sred[11]+1e-12f);
    const float ipr = rsqrtf(sred[4]+sred[12]+1e-12f);
    const float inr = rsqrtf(sred[5]+sred[13]+1e-12f);
    float pterm = fabsf(aph*iph + prr*ipr - apt*ipt);
    float nterm = fabsf(anh*inh + nrr*inr - ant*itn);
    #pragma unroll
    for (int off = 32; off; off >>= 1) {
        pterm += __shfl_xor(pterm, off);
        nterm += __shfl_xor(nterm, off);
    }
    __syncthreads();
    if (lane == 0) { sred[wid*2+0] = pterm; sred[wid*2+1] = nterm; }
    __syncthreads();
    if (r == 0)
        atomicAdd(out, fmaxf(sred[0]+sred[2] - sred[1]-sred[3] + MARGIN, 0.f) / (float)B);
}

// ---------------- launch ----------------

extern "C" void kernel_launch(void* const* d_in, const int* in_sizes, int n_in,
                              void* d_out, int out_size, void* d_ws, size_t ws_size,
                              hipStream_t stream) {
    const float* ent  = (const float*)d_in[0];
    const float* rel  = (const float*)d_in[1];
    const float* tmat = (const float*)d_in[2];
    const int* pos_h      = (const int*)d_in[3];
    const int* pos_t      = (const int*)d_in[4];
    const int* pos_r      = (const int*)d_in[5];
    const int* pos_type_r = (const int*)d_in[6];
    const int* neg_h      = (const int*)d_in[7];
    const int* neg_t      = (const int*)d_in[8];
    const int* neg_r      = (const int*)d_in[9];
    float* out = (float*)d_out;
    const int B = in_sizes[3];
    const int ntype = in_sizes[2] / (D * D);

    hipMemsetAsync(out, 0, sizeof(float), stream);

    if (B > MAX_B) {
        transr_fallback<<<B, 128, 0, stream>>>(
            ent, rel, tmat, pos_h, pos_t, pos_r, pos_type_r,
            neg_h, neg_t, neg_r, out, B);
        return;
    }

    fused_kernel<<<ntype, 512, 0, stream>>>(
        ent, rel, tmat, pos_h, pos_t, pos_r, pos_type_r,
        neg_h, neg_t, neg_r, out, B, 1.0f / (float)B);
}

// Round 12
// 52.816 us; speedup vs baseline: 19.4270x; 19.4270x over previous
//
#include <hip/hip_runtime.h>
#include <hip/hip_fp16.h>

#define D 128
#define MAX_B 8192
#define MARGIN 1.0f

// ---------------- fused single kernel: block == type ----------------
// 512 thr = 8 waves. Block scans pos_type_r for its type, builds ordered
// sample list in LDS, then each wave processes its samples autonomously.
// T staged in LDS as fp16 (32 KB): lane reads cols 4cg..+3 of a row as one
// ds_read_b64 (2x half2). v stays fp32 (uniform-address b128 broadcasts).

#define BFLY5(x) { x += __shfl_xor(x, 1); x += __shfl_xor(x, 2); x += __shfl_xor(x, 4); \
                   x += __shfl_xor(x, 8); x += __shfl_xor(x, 16); }

struct SampleRegs {
    float2 e0, e1, e2, e3;   // ent rows {ph,pt,nh,nt}, elems {2l, 2l+1}
    float4 rp, rn;           // rel rows (pos, neg), cols 4cg..+3
};

__device__ __forceinline__ void fetch_sample(
    SampleRegs& S, int o,
    const float* __restrict__ ent, const float* __restrict__ rel,
    const int* __restrict__ pos_h, const int* __restrict__ pos_t,
    const int* __restrict__ pos_r, const int* __restrict__ neg_h,
    const int* __restrict__ neg_t, const int* __restrict__ neg_r,
    int l, int cg)
{
    const size_t b0 = (size_t)pos_h[o] * D;
    const size_t b1 = (size_t)pos_t[o] * D;
    const size_t b2 = (size_t)neg_h[o] * D;
    const size_t b3 = (size_t)neg_t[o] * D;
    const size_t r0 = (size_t)pos_r[o] * D;
    const size_t r1 = (size_t)neg_r[o] * D;
    S.e0 = *(const float2*)&ent[b0 + 2 * l];
    S.e1 = *(const float2*)&ent[b1 + 2 * l];
    S.e2 = *(const float2*)&ent[b2 + 2 * l];
    S.e3 = *(const float2*)&ent[b3 + 2 * l];
    S.rp = *(const float4*)&rel[r0 + 4 * cg];
    S.rn = *(const float4*)&rel[r1 + 4 * cg];
}

__device__ __forceinline__ void commit_sample(float* vbw, const SampleRegs& S, int l) {
    *(float2*)&vbw[0 * D + 2 * l] = S.e0;
    *(float2*)&vbw[1 * D + 2 * l] = S.e1;
    *(float2*)&vbw[2 * D + 2 * l] = S.e2;
    *(float2*)&vbw[3 * D + 2 * l] = S.e3;
}

// one T row: b64 read of 4 fp16 cols, cvt, 16 FMA (4 roles x 4 cols)
#define TROW(IDX, S0, S1, S2, S3) do {                                        \
        const float2 raw = Tp[(IDX) * 32];                                    \
        const float2 f01 = __half22float2(*(const __half2*)&raw.x);           \
        const float2 f23 = __half22float2(*(const __half2*)&raw.y);           \
        a0.x = fmaf(f01.x,(S0),a0.x); a0.y = fmaf(f01.y,(S0),a0.y);           \
        a0.z = fmaf(f23.x,(S0),a0.z); a0.w = fmaf(f23.y,(S0),a0.w);           \
        a1.x = fmaf(f01.x,(S1),a1.x); a1.y = fmaf(f01.y,(S1),a1.y);           \
        a1.z = fmaf(f23.x,(S1),a1.z); a1.w = fmaf(f23.y,(S1),a1.w);           \
        a2.x = fmaf(f01.x,(S2),a2.x); a2.y = fmaf(f01.y,(S2),a2.y);           \
        a2.z = fmaf(f23.x,(S2),a2.z); a2.w = fmaf(f23.y,(S2),a2.w);           \
        a3.x = fmaf(f01.x,(S3),a3.x); a3.y = fmaf(f01.y,(S3),a3.y);           \
        a3.z = fmaf(f23.x,(S3),a3.z); a3.w = fmaf(f23.y,(S3),a3.w);           \
    } while (0)

// matvec for ONE sample + full score, within one wave.
__device__ __forceinline__ float sample_score(
    const __half2* __restrict__ Th, const float* __restrict__ vbw,
    int h, int cg, float4 rp, float4 rn)
{
    const float4* __restrict__ vv = (const float4*)vbw;   // [4 roles][32]
    // half2 base of (row = 64h, col = 4cg); row stride = 64 half2 = 32 float2
    const float2* __restrict__ Tp =
        (const float2*)(Th + (size_t)(h * 64) * 64 + 2 * cg);
    float4 a0 = make_float4(0.f, 0.f, 0.f, 0.f), a1 = a0, a2 = a0, a3 = a0;
    const int vb0 = h * 16;
    #pragma unroll 4
    for (int rg = 0; rg < 16; ++rg) {
        const int vi = vb0 + rg;
        const float4 w0 = vv[0 * 32 + vi];   // uniform-addr broadcast b128
        const float4 w1 = vv[1 * 32 + vi];
        const float4 w2 = vv[2 * 32 + vi];
        const float4 w3 = vv[3 * 32 + vi];
        TROW(rg * 4 + 0, w0.x, w1.x, w2.x, w3.x);
        TROW(rg * 4 + 1, w0.y, w1.y, w2.y, w3.y);
        TROW(rg * 4 + 2, w0.z, w1.z, w2.z, w3.z);
        TROW(rg * 4 + 3, w0.w, w1.w, w2.w, w3.w);
    }
    // combine the two row-halves (lanes l <-> l+32)
    a0.x += __shfl_xor(a0.x, 32); a0.y += __shfl_xor(a0.y, 32);
    a0.z += __shfl_xor(a0.z, 32); a0.w += __shfl_xor(a0.w, 32);
    a1.x += __shfl_xor(a1.x, 32); a1.y += __shfl_xor(a1.y, 32);
    a1.z += __shfl_xor(a1.z, 32); a1.w += __shfl_xor(a1.w, 32);
    a2.x += __shfl_xor(a2.x, 32); a2.y += __shfl_xor(a2.y, 32);
    a2.z += __shfl_xor(a2.z, 32); a2.w += __shfl_xor(a2.w, 32);
    a3.x += __shfl_xor(a3.x, 32); a3.y += __shfl_xor(a3.y, 32);
    a3.z += __shfl_xor(a3.z, 32); a3.w += __shfl_xor(a3.w, 32);

    float sph = a0.x*a0.x + a0.y*a0.y + a0.z*a0.z + a0.w*a0.w;
    float spt = a1.x*a1.x + a1.y*a1.y + a1.z*a1.z + a1.w*a1.w;
    float snh = a2.x*a2.x + a2.y*a2.y + a2.z*a2.z + a2.w*a2.w;
    float snt = a3.x*a3.x + a3.y*a3.y + a3.z*a3.z + a3.w*a3.w;
    float spr = rp.x*rp.x + rp.y*rp.y + rp.z*rp.z + rp.w*rp.w;
    float snr = rn.x*rn.x + rn.y*rn.y + rn.z*rn.z + rn.w*rn.w;
    BFLY5(sph); BFLY5(spt); BFLY5(snh); BFLY5(snt); BFLY5(spr); BFLY5(snr);
    const float iph = rsqrtf(sph + 1e-12f);
    const float ipt = rsqrtf(spt + 1e-12f);
    const float inh = rsqrtf(snh + 1e-12f);
    const float itn = rsqrtf(snt + 1e-12f);
    const float ipr = rsqrtf(spr + 1e-12f);
    const float inr = rsqrtf(snr + 1e-12f);
    float z = fabsf(a0.x*iph + rp.x*ipr - a1.x*ipt)
            + fabsf(a0.y*iph + rp.y*ipr - a1.y*ipt)
            + fabsf(a0.z*iph + rp.z*ipr - a1.z*ipt)
            + fabsf(a0.w*iph + rp.w*ipr - a1.w*ipt)
            - fabsf(a2.x*inh + rn.x*inr - a3.x*itn)
            - fabsf(a2.y*inh + rn.y*inr - a3.y*itn)
            - fabsf(a2.z*inh + rn.z*inr - a3.z*itn)
            - fabsf(a2.w*inh + rn.w*inr - a3.w*itn);
    BFLY5(z);
    return fmaxf(z + MARGIN, 0.f);
}

__global__ __launch_bounds__(512, 4) void fused_kernel(
    const float* __restrict__ ent,
    const float* __restrict__ rel,
    const float* __restrict__ tmat,
    const int* __restrict__ pos_h,
    const int* __restrict__ pos_t,
    const int* __restrict__ pos_r,
    const int* __restrict__ type_r,
    const int* __restrict__ neg_h,
    const int* __restrict__ neg_t,
    const int* __restrict__ neg_r,
    float* __restrict__ out,
    int B, float inv_B)
{
    const int t   = blockIdx.x;        // this block's type
    const int tid = threadIdx.x;
    const int l   = tid & 63;
    const int w   = tid >> 6;          // wave 0..7
    const int cg  = l & 31;
    const int h   = l >> 5;

    __shared__ __half2 T_h2[D * D / 2];  // 32 KB row-major fp16 T
    __shared__ float   vbuf[8][4][D];    // 16 KB per-wave role-major v
    __shared__ int     list[64];
    __shared__ int     wsumi[8];
    __shared__ float   wsumf[8];

    // ---- scan pos_type_r: thread tid covers samples [tid*per, +per) ----
    const int per = (B + 511) >> 9;    // == 16 at B=8192
    int vals[16];
    const int base = tid * per;
    int mc = 0;
    if (per == 16 && base + 15 < B) {
        const int4* vp = (const int4*)(type_r + base);
        #pragma unroll
        for (int k = 0; k < 4; ++k) {
            const int4 v = vp[k];
            vals[4*k+0] = v.x; vals[4*k+1] = v.y;
            vals[4*k+2] = v.z; vals[4*k+3] = v.w;
        }
    } else {
        for (int j = 0; j < 16; ++j) {
            const int s = base + j;
            vals[j] = (j < per && s < B) ? type_r[s] : -1;
        }
    }
    #pragma unroll
    for (int j = 0; j < 16; ++j) mc += (vals[j] == t);

    // ---- stage T as fp16: thread reads 32 floats (8 float4), cvt, write ----
    {
        const float4* Tg = (const float4*)(tmat + (size_t)t * (D * D));
        float4 tv[8];
        #pragma unroll
        for (int j = 0; j < 8; ++j) tv[j] = Tg[tid * 8 + j];
        __half2* Td = T_h2 + tid * 16;
        #pragma unroll
        for (int j = 0; j < 8; ++j) {
            Td[2*j]   = __float22half2_rn(make_float2(tv[j].x, tv[j].y));
            Td[2*j+1] = __float22half2_rn(make_float2(tv[j].z, tv[j].w));
        }
    }

    // ---- block-wide exclusive prefix of mc ----
    int inc = mc;
    #pragma unroll
    for (int off = 1; off < 64; off <<= 1) {
        const int tv = __shfl_up(inc, off);
        if (l >= off) inc += tv;
    }
    if (l == 63) wsumi[w] = inc;
    __syncthreads();                   // wsumi + T_h2 visible
    int wbase = 0, cnt = 0;
    #pragma unroll
    for (int k = 0; k < 8; ++k) {
        const int s = wsumi[k];
        wbase += (k < w) ? s : 0;
        cnt += s;
    }
    const int excl = wbase + inc - mc;

    float wl = 0.f;
    for (int r0 = 0;; r0 += 64) {
        // write this round's window [r0, r0+64) of the ordered match list
        {
            int g = excl;
            #pragma unroll
            for (int j = 0; j < 16; ++j) {
                if (vals[j] == t) {
                    const int wr = g - r0;
                    if (wr >= 0 && wr < 64) list[wr] = base + j;
                    ++g;
                }
            }
        }
        __syncthreads();               // list visible
        const int wcnt = min(cnt - r0, 64);
        int sidx[8];
        int nk = 0;
        #pragma unroll
        for (int k = 0; k < 8; ++k) {
            const int rank = w + 8 * k;
            if (rank < wcnt) sidx[nk++] = list[rank];
        }
        __syncthreads();               // reads done before next window write

        if (nk > 0) {
            float* vbw = &vbuf[w][0][0];
            SampleRegs A, Bq;
            fetch_sample(A, sidx[0], ent, rel, pos_h, pos_t, pos_r,
                         neg_h, neg_t, neg_r, l, cg);
            for (int k = 0;; ++k) {
                commit_sample(vbw, A, l);
                const bool more = (k + 1) < nk;
                if (more)
                    fetch_sample(Bq, sidx[k + 1], ent, rel, pos_h, pos_t, pos_r,
                                 neg_h, neg_t, neg_r, l, cg);
                wl += sample_score(T_h2, vbw, h, cg, A.rp, A.rn);
                if (!more) break;
                A = Bq;
            }
        }
        if (r0 + 64 >= cnt) break;
    }

    // ---- block reduction, one atomic ----
    __syncthreads();
    if (l == 0) wsumf[w] = wl;
    __syncthreads();
    if (tid == 0) {
        float s = 0.f;
        #pragma unroll
        for (int k = 0; k < 8; ++k) s += wsumf[k];
        if (s != 0.f) atomicAdd(out, s * inv_B);
    }
}

// ---------------- fallback (round-1 per-sample kernel) ----------------

__global__ __launch_bounds__(128) void transr_fallback(
    const float* __restrict__ ent, const float* __restrict__ rel,
    const float* __restrict__ tmat,
    const int* __restrict__ pos_h, const int* __restrict__ pos_t,
    const int* __restrict__ pos_r, const int* __restrict__ pos_type_r,
    const int* __restrict__ neg_h, const int* __restrict__ neg_t,
    const int* __restrict__ neg_r, float* __restrict__ out, int B)
{
    const int b = blockIdx.x;
    const int r = threadIdx.x;
    const int lane = r & 63;
    const int wid = r >> 6;
    __shared__ float4 vcomb[D];
    __shared__ float sred[16];
    vcomb[r] = make_float4(ent[(size_t)pos_h[b]*D + r], ent[(size_t)pos_t[b]*D + r],
                           ent[(size_t)neg_h[b]*D + r], ent[(size_t)neg_t[b]*D + r]);
    const float prr = rel[(size_t)pos_r[b] * D + r];
    const float nrr = rel[(size_t)neg_r[b] * D + r];
    __syncthreads();
    const float* __restrict__ T = tmat + (size_t)pos_type_r[b] * (D * D);
    float aph = 0.f, apt = 0.f, anh = 0.f, ant = 0.f;
    #pragma unroll 8
    for (int d = 0; d < D; ++d) {
        const float t = T[d * D + r];
        const float4 v = vcomb[d];
        aph = fmaf(v.x, t, aph); apt = fmaf(v.y, t, apt);
        anh = fmaf(v.z, t, anh); ant = fmaf(v.w, t, ant);
    }
    float s0 = aph*aph, s1 = apt*apt, s2 = anh*anh, s3 = ant*ant;
    float s4 = prr*prr, s5 = nrr*nrr;
    #pragma unroll
    for (int off = 32; off; off >>= 1) {
        s0 += __shfl_xor(s0, off); s1 += __shfl_xor(s1, off);
        s2 += __shfl_xor(s2, off); s3 += __shfl_xor(s3, off);
        s4 += __shfl_xor(s4, off); s5 += __shfl_xor(s5, off);
    }
    if (lane == 0) {
        sred[wid*8+0]=s0; sred[wid*8+1]=s1; sred[wid*8+2]=s2;
        sred[wid*8+3]=s3; sred[wid*8+4]=s4; sred[wid*8+5]=s5;
    }
    __syncthreads();
    const float iph = rsqrtf(sred[0]+sred[8] +1e-12f);
    const float ipt = rsqrtf(sred[1]+sred[9] +1e-12f);
    const float inh = rsqrtf(sred[2]+sred[10]+1e-12f);
    const float itn = rsqrtf(sred[3]+sred[11]+1e-12f);
    const float ipr = rsqrtf(sred[4]+sred[12]+1e-12f);
    const float inr = rsqrtf(sred[5]+sred[13]+1e-12f);
    float pterm = fabsf(aph*iph + prr*ipr - apt*ipt);
    float nterm = fabsf(anh*inh + nrr*inr - ant*itn);
    #pragma unroll
    for (int off = 32; off; off >>= 1) {
        pterm += __shfl_xor(pterm, off);
        nterm += __shfl_xor(nterm, off);
    }
    __syncthreads();
    if (lane == 0) { sred[wid*2+0] = pterm; sred[wid*2+1] = nterm; }
    __syncthreads();
    if (r == 0)
        atomicAdd(out, fmaxf(sred[0]+sred[2] - sred[1]-sred[3] + MARGIN, 0.f) / (float)B);
}

// ---------------- launch ----------------

extern "C" void kernel_launch(void* const* d_in, const int* in_sizes, int n_in,
                              void* d_out, int out_size, void* d_ws, size_t ws_size,
                              hipStream_t stream) {
    const float* ent  = (const float*)d_in[0];
    const float* rel  = (const float*)d_in[1];
    const float* tmat = (const float*)d_in[2];
    const int* pos_h      = (const int*)d_in[3];
    const int* pos_t      = (const int*)d_in[4];
    const int* pos_r      = (const int*)d_in[5];
    const int* pos_type_r = (const int*)d_in[6];
    const int* neg_h      = (const int*)d_in[7];
    const int* neg_t      = (const int*)d_in[8];
    const int* neg_r      = (const int*)d_in[9];
    float* out = (float*)d_out;
    const int B = in_sizes[3];
    const int ntype = in_sizes[2] / (D * D);

    hipMemsetAsync(out, 0, sizeof(float), stream);

    if (B > MAX_B) {
        transr_fallback<<<B, 128, 0, stream>>>(
            ent, rel, tmat, pos_h, pos_t, pos_r, pos_type_r,
            neg_h, neg_t, neg_r, out, B);
        return;
    }

    fused_kernel<<<ntype, 512, 0, stream>>>(
        ent, rel, tmat, pos_h, pos_t, pos_r, pos_type_r,
        neg_h, neg_t, neg_r, out, B, 1.0f / (float)B);
}